// Round 2
// baseline (2074.893 us; speedup 1.0000x reference)
//
#include <hip/hip_runtime.h>

typedef unsigned short u16;
typedef __bf16 bf16_t;
typedef bf16_t bf16x8 __attribute__((ext_vector_type(8)));
typedef float f32x4 __attribute__((ext_vector_type(4)));
typedef u16 u16x8 __attribute__((ext_vector_type(8)));

#define B_   4
#define L_   2048
#define HS_  2048
#define NH_  32
#define HD_  64
#define KK_  16
#define NM_  128
#define M_   (B_*L_)   // 8192

__device__ __forceinline__ u16 f2bf(float f) {
  unsigned u = __float_as_uint(f);
  u += 0x7FFFu + ((u >> 16) & 1u);   // RNE
  return (u16)(u >> 16);
}
__device__ __forceinline__ float bf2f(u16 u) {
  return __uint_as_float(((unsigned)u) << 16);
}

__device__ __forceinline__ float wsum(float v) {
#pragma unroll
  for (int m = 32; m > 0; m >>= 1) v += __shfl_xor(v, m, 64);
  return v;
}

// ---------------- cast f32 -> bf16 (8 elems/thread) ----------------
__global__ __launch_bounds__(256) void cast_f32_bf16(const float* __restrict__ in,
                                                     u16* __restrict__ out, int n) {
  int i = (blockIdx.x * 256 + threadIdx.x) * 8;
  if (i >= n) return;
  float4 a = *(const float4*)(in + i);
  float4 b = *(const float4*)(in + i + 4);
  u16x8 o;
  o[0]=f2bf(a.x); o[1]=f2bf(a.y); o[2]=f2bf(a.z); o[3]=f2bf(a.w);
  o[4]=f2bf(b.x); o[5]=f2bf(b.y); o[6]=f2bf(b.z); o[7]=f2bf(b.w);
  *(u16x8*)(out + i) = o;
}

// ---------------- bf16 MFMA GEMM, C = A(MxK) * Bt(NxK)^T ----------------
#define BM 128
#define BN 128
#define BK 32
#define LDT 40   // padded LDS row (bf16 elems): 80B stride -> 2-way banks max (free)

template <bool BF16OUT>
__global__ __launch_bounds__(256) void gemm_nt(const u16* __restrict__ A,
                                               const u16* __restrict__ Bt,
                                               void* __restrict__ Cv,
                                               int M, int N, int K) {
  __shared__ u16 As[BM * LDT];
  __shared__ u16 Bs[BN * LDT];
  int tid  = threadIdx.x;
  int lane = tid & 63, wave = tid >> 6;
  int quad = lane >> 4, l16 = lane & 15;
  int bM = blockIdx.x * BM, bN = blockIdx.y * BN;
  int wM = (wave >> 1) * 64, wN = (wave & 1) * 64;
  int r0 = tid >> 2, c0 = (tid & 3) * 8;
  const u16* Ap = A + (size_t)bM * K;
  const u16* Bp = Bt + (size_t)bN * K;
  f32x4 acc[4][4] = {};
  u16x8 pa0 = *(const u16x8*)(Ap + (size_t)r0 * K + c0);
  u16x8 pa1 = *(const u16x8*)(Ap + (size_t)(r0 + 64) * K + c0);
  u16x8 pb0 = *(const u16x8*)(Bp + (size_t)r0 * K + c0);
  u16x8 pb1 = *(const u16x8*)(Bp + (size_t)(r0 + 64) * K + c0);
  int nk = K / BK;
  for (int kt = 0; kt < nk; ++kt) {
    *(u16x8*)&As[r0 * LDT + c0]        = pa0;
    *(u16x8*)&As[(r0 + 64) * LDT + c0] = pa1;
    *(u16x8*)&Bs[r0 * LDT + c0]        = pb0;
    *(u16x8*)&Bs[(r0 + 64) * LDT + c0] = pb1;
    __syncthreads();
    if (kt + 1 < nk) {
      int k0 = (kt + 1) * BK + c0;
      pa0 = *(const u16x8*)(Ap + (size_t)r0 * K + k0);
      pa1 = *(const u16x8*)(Ap + (size_t)(r0 + 64) * K + k0);
      pb0 = *(const u16x8*)(Bp + (size_t)r0 * K + k0);
      pb1 = *(const u16x8*)(Bp + (size_t)(r0 + 64) * K + k0);
    }
    bf16x8 af[4], bfr[4];
#pragma unroll
    for (int i = 0; i < 4; ++i) {
      u16x8 t = *(const u16x8*)&As[(wM + i * 16 + l16) * LDT + quad * 8];
      af[i] = __builtin_bit_cast(bf16x8, t);
    }
#pragma unroll
    for (int j = 0; j < 4; ++j) {
      u16x8 t = *(const u16x8*)&Bs[(wN + j * 16 + l16) * LDT + quad * 8];
      bfr[j] = __builtin_bit_cast(bf16x8, t);
    }
#pragma unroll
    for (int i = 0; i < 4; ++i) {
#pragma unroll
      for (int j = 0; j < 4; ++j)
        acc[i][j] = __builtin_amdgcn_mfma_f32_16x16x32_bf16(af[i], bfr[j], acc[i][j], 0, 0, 0);
    }
    __syncthreads();
  }
  // C/D layout: col = lane&15, row = quad*4 + r  [m89-verified]
#pragma unroll
  for (int i = 0; i < 4; ++i) {
#pragma unroll
    for (int j = 0; j < 4; ++j) {
      int row = bM + wM + i * 16 + quad * 4;
      int col = bN + wN + j * 16 + l16;
      if (BF16OUT) {
        u16* cp = (u16*)Cv + (size_t)row * N + col;
#pragma unroll
        for (int r = 0; r < 4; ++r) cp[(size_t)r * N] = f2bf(acc[i][j][r]);
      } else {
        float* cp = (float*)Cv + (size_t)row * N + col;
#pragma unroll
        for (int r = 0; r < 4; ++r) cp[(size_t)r * N] = acc[i][j][r];
      }
    }
  }
}

// ---------------- lr projection: Sig[m,h] = sigmoid(hs_m . lrw_h + lrb_h)/HD ----------------
__global__ __launch_bounds__(256) void sig_kernel(const u16* __restrict__ hsb,
                                                  const u16* __restrict__ lrwb,
                                                  const float* __restrict__ lrb,
                                                  float* __restrict__ Sig) {
  __shared__ u16 Bs[32 * LDT];
  int tid = threadIdx.x;
  int lane = tid & 63, wave = tid >> 6;
  int quad = lane >> 4, l16 = lane & 15;
  int m0 = blockIdx.x * 64 + wave * 16;
  f32x4 acc0 = {}, acc1 = {};
  for (int kt = 0; kt < HS_ / BK; ++kt) {
    int k0 = kt * BK;
    if (tid < 128) {
      int r = tid >> 2, c8 = (tid & 3) * 8;
      *(u16x8*)&Bs[r * LDT + c8] = *(const u16x8*)(lrwb + (size_t)r * HS_ + k0 + c8);
    }
    __syncthreads();
    u16x8 ta = *(const u16x8*)(hsb + (size_t)(m0 + l16) * HS_ + k0 + quad * 8);
    u16x8 t0 = *(const u16x8*)&Bs[l16 * LDT + quad * 8];
    u16x8 t1 = *(const u16x8*)&Bs[(16 + l16) * LDT + quad * 8];
    bf16x8 af  = __builtin_bit_cast(bf16x8, ta);
    bf16x8 bf0 = __builtin_bit_cast(bf16x8, t0);
    bf16x8 bf1 = __builtin_bit_cast(bf16x8, t1);
    acc0 = __builtin_amdgcn_mfma_f32_16x16x32_bf16(af, bf0, acc0, 0, 0, 0);
    acc1 = __builtin_amdgcn_mfma_f32_16x16x32_bf16(af, bf1, acc1, 0, 0, 0);
    __syncthreads();
  }
#pragma unroll
  for (int j = 0; j < 2; ++j) {
    f32x4 a = j ? acc1 : acc0;
    int h = j * 16 + l16;
    float bias = lrb[h];
#pragma unroll
    for (int r = 0; r < 4; ++r) {
      int m = m0 + quad * 4 + r;
      float v = a[r] + bias;
      float s = (1.f / (1.f + expf(-v))) * (1.f / 64.f);
      Sig[(size_t)m * NH_ + h] = s;
    }
  }
}

// ---------------- TTT scan: one block per (b,h) chain ----------------
__global__ __launch_bounds__(1024) void ttt_scan(
    const u16* __restrict__ XQ, const u16* __restrict__ XK, const u16* __restrict__ XV,
    const float* __restrict__ Sig, const float* __restrict__ W1_0, const float* __restrict__ b1_0,
    const float* __restrict__ lnw, const float* __restrict__ lnb, const float* __restrict__ lti,
    float* __restrict__ Y) {
  __shared__ float W1t[64 * 68];          // W1t[d][c] = W1[c][d]; stride 68 floats
  __shared__ float xq_s[16 * 64], xk_s[16 * 64], grad_s[16 * 64];
  __shared__ float coef_s[16 * 16];
  __shared__ float b1_s[64];
  __shared__ float sig_s[16];
  __shared__ float tok_s[16];
  int tid = threadIdx.x;
  int d = tid & 63, k = tid >> 6;
  int bh = blockIdx.x;
  int b = bh >> 5, h = bh & 31;
  int quad = d >> 4, l16 = d & 15;
#pragma unroll
  for (int cc = 0; cc < 4; ++cc) {
    int c = k * 4 + cc;
    W1t[d * 68 + c] = W1_0[(size_t)h * 4096 + (size_t)c * 64 + d];
  }
  if (k == 0) b1_s[d] = b1_0[h * 64 + d];
  if (tid < 16) tok_s[tid] = fmaxf(1.0f / (float)(tid + 1) + lti[tid], 0.0f);
  float gamma = lnw[h * 64 + d], beta = lnb[h * 64 + d];
  __syncthreads();
  float tok_k = tok_s[k];
  float tok15 = tok_s[15];
  for (int n = 0; n < NM_; ++n) {
    size_t base = ((size_t)(b * L_ + n * KK_ + k)) * HS_ + h * HD_ + d;
    float xq_r = bf2f(XQ[base]), xk_r = bf2f(XK[base]), xv_r = bf2f(XV[base]);
    xq_s[k * 64 + d] = xq_r;
    xk_s[k * 64 + d] = xk_r;
    if (tid < 16) sig_s[tid] = Sig[(size_t)(b * L_ + n * KK_ + tid) * NH_ + h];
    __syncthreads();   // S1
    // Z1 = xk@W1 + b1 ; zq = xq@W1  (shared W1 read)
    float z = 0.f, zq = 0.f;
#pragma unroll
    for (int c4 = 0; c4 < 16; ++c4) {
      float4 w4 = *(const float4*)&W1t[d * 68 + c4 * 4];
      float4 a4 = *(const float4*)&xk_s[k * 64 + c4 * 4];
      float4 q4 = *(const float4*)&xq_s[k * 64 + c4 * 4];
      z  += a4.x * w4.x + a4.y * w4.y + a4.z * w4.z + a4.w * w4.w;
      zq += q4.x * w4.x + q4.y * w4.y + q4.z * w4.z + q4.w * w4.w;
    }
    z += b1_s[d];
    // fused LN-l2 backward over HD=64 (one wave per row)
    float mu = wsum(z) * (1.f / 64.f);
    float t0 = z - mu;
    float var = wsum(t0 * t0) * (1.f / 64.f);
    float rstd = 1.0f / sqrtf(var + 1e-6f);
    float xh = t0 * rstd;
    float gxh = (gamma * xh + beta - (xv_r - xk_r)) * gamma;
    float S1v = wsum(gxh);
    float S2v = wsum(gxh * xh);
    float grad = (64.f * gxh - S1v - xh * S2v) * (rstd * (1.f / 64.f));
    grad_s[k * 64 + d] = grad;
    // Attn[k][j], j = l16, partial over c-segment = quad (swizzled)
    float ap = 0.f;
#pragma unroll
    for (int i = 0; i < 16; ++i) {
      int c = quad * 16 + ((i + l16) & 15);
      ap += xq_s[k * 64 + c] * xk_s[l16 * 64 + c];
    }
    ap += __shfl_xor(ap, 16, 64);
    ap += __shfl_xor(ap, 32, 64);
    if (quad == 0) coef_s[k * 16 + l16] = (l16 <= k) ? tok_k * sig_s[l16] * (1.f + ap) : 0.f;
    __syncthreads();   // S2
    // Z1_bar = xq@W1 + b1 - sum_j coef[k][j]*grad[j][d]
    float zb = zq + b1_s[d];
#pragma unroll
    for (int j = 0; j < 16; ++j) zb -= coef_s[k * 16 + j] * grad_s[j * 64 + d];
    float mu2 = wsum(zb) * (1.f / 64.f);
    float t2 = zb - mu2;
    float var2 = wsum(t2 * t2) * (1.f / 64.f);
    float rstd2 = 1.0f / sqrtf(var2 + 1e-6f);
    Y[base] = xq_r + gamma * (t2 * rstd2) + beta;
    // state update
    float lg[16];
#pragma unroll
    for (int kk = 0; kk < 16; ++kk) lg[kk] = tok15 * sig_s[kk] * grad_s[kk * 64 + d];
    float4 wv = *(const float4*)&W1t[d * 68 + k * 4];   // own cells only
    float w0 = wv.x, w1 = wv.y, w2 = wv.z, w3 = wv.w;
#pragma unroll
    for (int kk = 0; kk < 16; ++kk) {
      float4 xk4 = *(const float4*)&xk_s[kk * 64 + k * 4];
      w0 -= xk4.x * lg[kk]; w1 -= xk4.y * lg[kk];
      w2 -= xk4.z * lg[kk]; w3 -= xk4.w * lg[kk];
    }
    float bnew = 0.f;
    if (k == 0) {
      float a0 = b1_s[d];
#pragma unroll
      for (int kk = 0; kk < 16; ++kk) a0 -= lg[kk];
      bnew = a0;
    }
    __syncthreads();   // S3 (all reads of W1t/b1_s/xk_s/grad_s done)
    *(float4*)&W1t[d * 68 + k * 4] = make_float4(w0, w1, w2, w3);
    if (k == 0) b1_s[d] = bnew;
    // next iteration's S1 separates these writes from their readers
  }
}

// ---------------- post-norm (LN over HS=2048) -> bf16 ----------------
__global__ __launch_bounds__(256) void postnorm(const float* __restrict__ Yin,
                                                const float* __restrict__ w,
                                                const float* __restrict__ bb,
                                                u16* __restrict__ Yn) {
  __shared__ float red[8];
  int row = blockIdx.x, tid = threadIdx.x;
  const float* x = Yin + (size_t)row * HS_ + tid * 8;
  float4 v0 = *(const float4*)(x);
  float4 v1 = *(const float4*)(x + 4);
  float s  = v0.x + v0.y + v0.z + v0.w + v1.x + v1.y + v1.z + v1.w;
  float ss = v0.x*v0.x + v0.y*v0.y + v0.z*v0.z + v0.w*v0.w
           + v1.x*v1.x + v1.y*v1.y + v1.z*v1.z + v1.w*v1.w;
#pragma unroll
  for (int m = 32; m > 0; m >>= 1) { s += __shfl_xor(s, m, 64); ss += __shfl_xor(ss, m, 64); }
  int wave = tid >> 6, lane = tid & 63;
  if (lane == 0) { red[wave] = s; red[4 + wave] = ss; }
  __syncthreads();
  float S  = red[0] + red[1] + red[2] + red[3];
  float SS = red[4] + red[5] + red[6] + red[7];
  float mu = S * (1.f / 2048.f);
  float var = SS * (1.f / 2048.f) - mu * mu;
  float rstd = 1.f / sqrtf(var + 1e-6f);
  const float* wp = w + tid * 8;
  const float* bp = bb + tid * 8;
  float vals[8] = {v0.x, v0.y, v0.z, v0.w, v1.x, v1.y, v1.z, v1.w};
  u16x8 o;
#pragma unroll
  for (int t = 0; t < 8; ++t) o[t] = f2bf(wp[t] * ((vals[t] - mu) * rstd) + bp[t]);
  *(u16x8*)(Yn + (size_t)row * HS_ + tid * 8) = o;
}

extern "C" void kernel_launch(void* const* d_in, const int* in_sizes, int n_in,
                              void* d_out, int out_size, void* d_ws, size_t ws_size,
                              hipStream_t stream) {
  (void)in_sizes; (void)n_in; (void)out_size; (void)ws_size;
  const float* hidden = (const float*)d_in[0];
  // d_in[1] = position_ids (unused)
  const float* q_w = (const float*)d_in[2];
  const float* k_w = (const float*)d_in[3];
  const float* v_w = (const float*)d_in[4];
  const float* o_w = (const float*)d_in[5];
  const float* W1  = (const float*)d_in[6];
  const float* b1i = (const float*)d_in[7];
  const float* lnw = (const float*)d_in[8];
  const float* lnb = (const float*)d_in[9];
  const float* lrw = (const float*)d_in[10];
  const float* lrb = (const float*)d_in[11];
  const float* lti = (const float*)d_in[12];
  const float* pnw = (const float*)d_in[13];
  const float* pnb = (const float*)d_in[14];
  float* out = (float*)d_out;

  // ---- workspace layout: total 137.125 MB ----
  char* w = (char*)d_ws;
  u16* hsb  = (u16*)w;  w += (size_t)16777216 * 2;   // bf16 hidden (32 MB); reused as Yn after scan
  u16* wb   = (u16*)w;  w += (size_t)4194304 * 2;    // bf16 weight, reused for q/k/v/o (8 MB)
  u16* lrwb = (u16*)w;  w += (size_t)65536 * 2;      // 128 KB
  u16* XQb  = (u16*)w;  w += (size_t)16777216 * 2;   // 32 MB
  u16* XKb  = (u16*)w;  w += (size_t)16777216 * 2;   // 32 MB
  u16* XVb  = (u16*)w;  w += (size_t)16777216 * 2;   // 32 MB
  float* Sg = (float*)w; w += (size_t)M_ * NH_ * 4;  // 1 MB
  u16* Yn = hsb;  // alias: hsb dead after projection GEMMs + sig

  cast_f32_bf16<<<8192, 256, 0, stream>>>(hidden, hsb, 16777216);
  cast_f32_bf16<<<32, 256, 0, stream>>>(lrw, lrwb, 65536);

  sig_kernel<<<128, 256, 0, stream>>>(hsb, lrwb, lrb, Sg);

  dim3 gg(M_ / BM, HS_ / BN);
  cast_f32_bf16<<<2048, 256, 0, stream>>>(q_w, wb, 4194304);
  gemm_nt<true><<<gg, 256, 0, stream>>>(hsb, wb, XQb, M_, HS_, HS_);
  cast_f32_bf16<<<2048, 256, 0, stream>>>(k_w, wb, 4194304);
  gemm_nt<true><<<gg, 256, 0, stream>>>(hsb, wb, XKb, M_, HS_, HS_);
  cast_f32_bf16<<<2048, 256, 0, stream>>>(v_w, wb, 4194304);
  gemm_nt<true><<<gg, 256, 0, stream>>>(hsb, wb, XVb, M_, HS_, HS_);

  ttt_scan<<<128, 1024, 0, stream>>>(XQb, XKb, XVb, Sg, W1, b1i, lnw, lnb, lti, out);

  postnorm<<<8192, 256, 0, stream>>>(out, pnw, pnb, Yn);

  cast_f32_bf16<<<2048, 256, 0, stream>>>(o_w, wb, 4194304);
  gemm_nt<false><<<gg, 256, 0, stream>>>(Yn, wb, out, M_, HS_, HS_);
}

// Round 4
// 1016.617 us; speedup vs baseline: 2.0410x; 2.0410x over previous
//
#include <hip/hip_runtime.h>

typedef unsigned short u16;
typedef unsigned int u32;
typedef __bf16 bf16_t;
typedef bf16_t bf16x8 __attribute__((ext_vector_type(8)));
typedef float f32x4 __attribute__((ext_vector_type(4)));
typedef u16 u16x8 __attribute__((ext_vector_type(8)));

#define B_   4
#define L_   2048
#define HS_  2048
#define NH_  32
#define HD_  64
#define KK_  16
#define NM_  128
#define M_   (B_*L_)   // 8192

__device__ __forceinline__ u16 f2bf(float f) {
  unsigned u = __float_as_uint(f);
  u += 0x7FFFu + ((u >> 16) & 1u);   // RNE
  return (u16)(u >> 16);
}
__device__ __forceinline__ float bf2f(u16 u) {
  return __uint_as_float(((unsigned)u) << 16);
}
__device__ __forceinline__ f32x4 vshfl_xor(f32x4 v, int m) {
  f32x4 r;
  r[0] = __shfl_xor(v[0], m, 64); r[1] = __shfl_xor(v[1], m, 64);
  r[2] = __shfl_xor(v[2], m, 64); r[3] = __shfl_xor(v[3], m, 64);
  return r;
}

// ---------------- cast f32 -> bf16 (8 elems/thread) ----------------
__global__ __launch_bounds__(256) void cast_f32_bf16(const float* __restrict__ in,
                                                     u16* __restrict__ out, int n) {
  int i = (blockIdx.x * 256 + threadIdx.x) * 8;
  if (i >= n) return;
  float4 a = *(const float4*)(in + i);
  float4 b = *(const float4*)(in + i + 4);
  u16x8 o;
  o[0]=f2bf(a.x); o[1]=f2bf(a.y); o[2]=f2bf(a.z); o[3]=f2bf(a.w);
  o[4]=f2bf(b.x); o[5]=f2bf(b.y); o[6]=f2bf(b.z); o[7]=f2bf(b.w);
  *(u16x8*)(out + i) = o;
}

// ---------------- bf16 MFMA GEMM, C = A(MxK) * Bt(NxK)^T ----------------
#define BM 128
#define BN 128
#define BK 32
#define LDT 40

template <bool BF16OUT>
__global__ __launch_bounds__(256) void gemm_nt(const u16* __restrict__ A,
                                               const u16* __restrict__ Bt,
                                               void* __restrict__ Cv,
                                               int M, int N, int K) {
  __shared__ u16 As[BM * LDT];
  __shared__ u16 Bs[BN * LDT];
  int tid  = threadIdx.x;
  int lane = tid & 63, wave = tid >> 6;
  int quad = lane >> 4, l16 = lane & 15;
  int bM = blockIdx.x * BM, bN = blockIdx.y * BN;
  int wM = (wave >> 1) * 64, wN = (wave & 1) * 64;
  int r0 = tid >> 2, c0 = (tid & 3) * 8;
  const u16* Ap = A + (size_t)bM * K;
  const u16* Bp = Bt + (size_t)bN * K;
  f32x4 acc[4][4] = {};
  u16x8 pa0 = *(const u16x8*)(Ap + (size_t)r0 * K + c0);
  u16x8 pa1 = *(const u16x8*)(Ap + (size_t)(r0 + 64) * K + c0);
  u16x8 pb0 = *(const u16x8*)(Bp + (size_t)r0 * K + c0);
  u16x8 pb1 = *(const u16x8*)(Bp + (size_t)(r0 + 64) * K + c0);
  int nk = K / BK;
  for (int kt = 0; kt < nk; ++kt) {
    *(u16x8*)&As[r0 * LDT + c0]        = pa0;
    *(u16x8*)&As[(r0 + 64) * LDT + c0] = pa1;
    *(u16x8*)&Bs[r0 * LDT + c0]        = pb0;
    *(u16x8*)&Bs[(r0 + 64) * LDT + c0] = pb1;
    __syncthreads();
    if (kt + 1 < nk) {
      int k0 = (kt + 1) * BK + c0;
      pa0 = *(const u16x8*)(Ap + (size_t)r0 * K + k0);
      pa1 = *(const u16x8*)(Ap + (size_t)(r0 + 64) * K + k0);
      pb0 = *(const u16x8*)(Bp + (size_t)r0 * K + k0);
      pb1 = *(const u16x8*)(Bp + (size_t)(r0 + 64) * K + k0);
    }
    bf16x8 af[4], bfr[4];
#pragma unroll
    for (int i = 0; i < 4; ++i) {
      u16x8 t = *(const u16x8*)&As[(wM + i * 16 + l16) * LDT + quad * 8];
      af[i] = __builtin_bit_cast(bf16x8, t);
    }
#pragma unroll
    for (int j = 0; j < 4; ++j) {
      u16x8 t = *(const u16x8*)&Bs[(wN + j * 16 + l16) * LDT + quad * 8];
      bfr[j] = __builtin_bit_cast(bf16x8, t);
    }
#pragma unroll
    for (int i = 0; i < 4; ++i) {
#pragma unroll
      for (int j = 0; j < 4; ++j)
        acc[i][j] = __builtin_amdgcn_mfma_f32_16x16x32_bf16(af[i], bfr[j], acc[i][j], 0, 0, 0);
    }
    __syncthreads();
  }
#pragma unroll
  for (int i = 0; i < 4; ++i) {
#pragma unroll
    for (int j = 0; j < 4; ++j) {
      int row = bM + wM + i * 16 + quad * 4;
      int col = bN + wN + j * 16 + l16;
      if (BF16OUT) {
        u16* cp = (u16*)Cv + (size_t)row * N + col;
#pragma unroll
        for (int r = 0; r < 4; ++r) cp[(size_t)r * N] = f2bf(acc[i][j][r]);
      } else {
        float* cp = (float*)Cv + (size_t)row * N + col;
#pragma unroll
        for (int r = 0; r < 4; ++r) cp[(size_t)r * N] = acc[i][j][r];
      }
    }
  }
}

// ---------------- lr projection: Sig[m,h] = sigmoid(hs_m . lrw_h + lrb_h)/HD ----------------
__global__ __launch_bounds__(256) void sig_kernel(const u16* __restrict__ hsb,
                                                  const u16* __restrict__ lrwb,
                                                  const float* __restrict__ lrb,
                                                  float* __restrict__ Sig) {
  __shared__ u16 Bs[32 * LDT];
  int tid = threadIdx.x;
  int lane = tid & 63, wave = tid >> 6;
  int quad = lane >> 4, l16 = lane & 15;
  int m0 = blockIdx.x * 64 + wave * 16;
  f32x4 acc0 = {}, acc1 = {};
  for (int kt = 0; kt < HS_ / BK; ++kt) {
    int k0 = kt * BK;
    if (tid < 128) {
      int r = tid >> 2, c8 = (tid & 3) * 8;
      *(u16x8*)&Bs[r * LDT + c8] = *(const u16x8*)(lrwb + (size_t)r * HS_ + k0 + c8);
    }
    __syncthreads();
    u16x8 ta = *(const u16x8*)(hsb + (size_t)(m0 + l16) * HS_ + k0 + quad * 8);
    u16x8 t0 = *(const u16x8*)&Bs[l16 * LDT + quad * 8];
    u16x8 t1 = *(const u16x8*)&Bs[(16 + l16) * LDT + quad * 8];
    bf16x8 af  = __builtin_bit_cast(bf16x8, ta);
    bf16x8 bf0 = __builtin_bit_cast(bf16x8, t0);
    bf16x8 bf1 = __builtin_bit_cast(bf16x8, t1);
    acc0 = __builtin_amdgcn_mfma_f32_16x16x32_bf16(af, bf0, acc0, 0, 0, 0);
    acc1 = __builtin_amdgcn_mfma_f32_16x16x32_bf16(af, bf1, acc1, 0, 0, 0);
    __syncthreads();
  }
#pragma unroll
  for (int j = 0; j < 2; ++j) {
    f32x4 a = j ? acc1 : acc0;
    int h = j * 16 + l16;
    float bias = lrb[h];
#pragma unroll
    for (int r = 0; r < 4; ++r) {
      int m = m0 + quad * 4 + r;
      float v = a[r] + bias;
      float s = (1.f / (1.f + expf(-v))) * (1.f / 64.f);
      Sig[(size_t)m * NH_ + h] = s;
    }
  }
}

// ---------------- MFMA TTT scan: one 256-thread block per (b,h) chain ----------------
// Wave w owns output cols d = w*16+l16. W1^T master in registers (C-layout,
// 16 f32/lane). Per-step matmuls via mfma_f32_16x16x32_bf16.
// sig_j lives in gradT ONLY; coefA is -tok_k*(1+attn)*[j<=k]  (R3 bug: sig twice).
__global__ __launch_bounds__(256) void ttt_scan_mfma(
    const u16* __restrict__ XQ, const u16* __restrict__ XK, const u16* __restrict__ XV,
    const float* __restrict__ Sig, const float* __restrict__ W1_0, const float* __restrict__ b1_0,
    const float* __restrict__ lnw, const float* __restrict__ lnb, const float* __restrict__ lti,
    float* __restrict__ Y) {
  __shared__ u16 xkq[32 * 72];     // rows 0-15: xk, 16-31: xq (bf16)
  __shared__ u16 W1t[64 * 72];     // bf16 W1^T [d_out][d_in]
  __shared__ u16 gradT[64 * 40];   // [d][k] = sig[k]*grad[k][d]; cols 16..31 zero
  __shared__ u16 coefA[16 * 40];   // [k][j] = -tok_k*(1+attn)[j<=k]; cols 16..31 zero
  __shared__ u16 xkT[64 * 40];     // [c][k] = -tok15*xk[k][c]; cols 16..31 zero
  __shared__ float diff[16 * 68];  // xv - xk (f32)
  __shared__ float red1[128], red2[128], red3[128];
  __shared__ float sig_s[16];

  int tid = threadIdx.x, wave = tid >> 6, lane = tid & 63;
  int quad = lane >> 4, l16 = lane & 15;
  int bh = blockIdx.x, b = bh >> 5, h = bh & 31;
  int dcol = wave * 16 + l16;

  {
    u32* p = (u32*)gradT; for (int i = tid; i < 1280; i += 256) p[i] = 0;
    u32* q = (u32*)coefA; for (int i = tid; i < 320;  i += 256) q[i] = 0;
    u32* s = (u32*)xkT;   for (int i = tid; i < 1280; i += 256) s[i] = 0;
  }

  // W1 master: master[m][r] = W1[c=dcol][d=m*16+quad*4+r]
  f32x4 master[4];
  const float* wsrc = W1_0 + (size_t)h * 4096 + (size_t)dcol * 64;
#pragma unroll
  for (int m = 0; m < 4; ++m)
#pragma unroll
    for (int r = 0; r < 4; ++r) master[m][r] = wsrc[m * 16 + quad * 4 + r];
#pragma unroll
  for (int m = 0; m < 4; ++m)
#pragma unroll
    for (int r = 0; r < 4; ++r)
      W1t[(m * 16 + quad * 4 + r) * 72 + dcol] = f2bf(master[m][r]);

  float b1_reg = b1_0[h * 64 + dcol];
  float gamma_r = lnw[h * 64 + dcol], beta_r = lnb[h * 64 + dcol];
  f32x4 tok4;
#pragma unroll
  for (int r = 0; r < 4; ++r) {
    int kk = quad * 4 + r;
    tok4[r] = fmaxf(1.0f / (float)(kk + 1) + lti[kk], 0.0f);
  }
  float tok15 = fmaxf(1.0f / 16.0f + lti[15], 0.0f);

  int lrow = (tid < 128) ? (tid >> 3) : ((tid - 128) >> 3);
  int lc8  = (tid & 7) * 8;
  size_t rowstep = (size_t)HS_;
  size_t gb0 = ((size_t)(b * L_ + lrow)) * HS_ + h * HD_ + lc8;

  u16x8 rq, rv, rk;
  float rsig = 0.f;
  {
    size_t g = gb0;
    if (tid < 128) { rq = *(const u16x8*)(XQ + g); rv = *(const u16x8*)(XV + g); rk = *(const u16x8*)(XK + g); }
    else           { rk = *(const u16x8*)(XK + g); }
    if (tid < 16) rsig = Sig[(size_t)(b * L_ + tid) * NH_ + h];
  }
  __syncthreads();

  for (int n = 0; n < NM_; ++n) {
    // ---- deposit prefetched step-n data ----
    if (tid < 128) {
      *(u16x8*)&xkq[(16 + lrow) * 72 + lc8] = rq;
      float4 d0, d1;
      d0.x = bf2f(rv[0]) - bf2f(rk[0]); d0.y = bf2f(rv[1]) - bf2f(rk[1]);
      d0.z = bf2f(rv[2]) - bf2f(rk[2]); d0.w = bf2f(rv[3]) - bf2f(rk[3]);
      d1.x = bf2f(rv[4]) - bf2f(rk[4]); d1.y = bf2f(rv[5]) - bf2f(rk[5]);
      d1.z = bf2f(rv[6]) - bf2f(rk[6]); d1.w = bf2f(rv[7]) - bf2f(rk[7]);
      *(float4*)&diff[lrow * 68 + lc8]     = d0;
      *(float4*)&diff[lrow * 68 + lc8 + 4] = d1;
    } else {
      *(u16x8*)&xkq[lrow * 72 + lc8] = rk;
#pragma unroll
      for (int i = 0; i < 8; ++i)
        xkT[(lc8 + i) * 40 + lrow] = f2bf(-tok15 * bf2f(rk[i]));
    }
    if (tid < 16) sig_s[tid] = rsig;
    __syncthreads();   // S1

    // ---- prefetch step n+1 ----
    if (n + 1 < NM_) {
      size_t g = gb0 + (size_t)(n + 1) * KK_ * rowstep;
      if (tid < 128) { rq = *(const u16x8*)(XQ + g); rv = *(const u16x8*)(XV + g); rk = *(const u16x8*)(XK + g); }
      else           { rk = *(const u16x8*)(XK + g); }
      if (tid < 16) rsig = Sig[(size_t)(b * L_ + (n + 1) * KK_ + tid) * NH_ + h];
    }

    // ---- Z MFMAs (+ Attn on wave 0) ----
    bf16x8 fxk[2], fxq[2], fw[2];
#pragma unroll
    for (int kc = 0; kc < 2; ++kc) {
      fxk[kc] = __builtin_bit_cast(bf16x8, *(const u16x8*)&xkq[l16 * 72 + kc * 32 + quad * 8]);
      fxq[kc] = __builtin_bit_cast(bf16x8, *(const u16x8*)&xkq[(16 + l16) * 72 + kc * 32 + quad * 8]);
      fw[kc]  = __builtin_bit_cast(bf16x8, *(const u16x8*)&W1t[(wave * 16 + l16) * 72 + kc * 32 + quad * 8]);
    }
    f32x4 z1 = {}, zq = {};
#pragma unroll
    for (int kc = 0; kc < 2; ++kc) {
      z1 = __builtin_amdgcn_mfma_f32_16x16x32_bf16(fxk[kc], fw[kc], z1, 0, 0, 0);
      zq = __builtin_amdgcn_mfma_f32_16x16x32_bf16(fxq[kc], fw[kc], zq, 0, 0, 0);
    }
    if (wave == 0) {
      f32x4 at = {};
#pragma unroll
      for (int kc = 0; kc < 2; ++kc)
        at = __builtin_amdgcn_mfma_f32_16x16x32_bf16(fxq[kc], fxk[kc], at, 0, 0, 0);
#pragma unroll
      for (int r = 0; r < 4; ++r) {
        int kk = quad * 4 + r;
        // sig_j lives in gradT; do NOT multiply it here (R3 bug).
        float c = (l16 <= kk) ? tok4[r] * (1.0f + at[r]) : 0.0f;
        coefA[kk * 40 + l16] = f2bf(-c);
      }
    }
#pragma unroll
    for (int r = 0; r < 4; ++r) z1[r] += b1_reg;

    // ---- LN-bwd round 1: mean & var ----
    {
      f32x4 s1 = z1, s2 = z1 * z1;
#pragma unroll
      for (int m = 1; m <= 8; m <<= 1) { s1 = s1 + vshfl_xor(s1, m); s2 = s2 + vshfl_xor(s2, m); }
      if (l16 == 0) {
#pragma unroll
        for (int r = 0; r < 4; ++r) {
          red1[quad * 32 + r * 8 + wave]     = s1[r];
          red1[quad * 32 + r * 8 + 4 + wave] = s2[r];
        }
      }
    }
    __syncthreads();   // S2
    f32x4 mu, rstd;
#pragma unroll
    for (int r = 0; r < 4; ++r) {
      f32x4 a = *(const f32x4*)&red1[quad * 32 + r * 8];
      f32x4 c = *(const f32x4*)&red1[quad * 32 + r * 8 + 4];
      float S = a[0] + a[1] + a[2] + a[3];
      float SS = c[0] + c[1] + c[2] + c[3];
      mu[r] = S * (1.0f / 64.0f);
      float var = SS * (1.0f / 64.0f) - mu[r] * mu[r];
      rstd[r] = 1.0f / sqrtf(var + 1e-6f);
    }
    // ---- gxh + round 2 ----
    f32x4 xh, gxh;
#pragma unroll
    for (int r = 0; r < 4; ++r) {
      float dd = diff[(quad * 4 + r) * 68 + dcol];
      xh[r] = (z1[r] - mu[r]) * rstd[r];
      gxh[r] = (gamma_r * xh[r] + beta_r - dd) * gamma_r;
    }
    {
      f32x4 s1 = gxh, s2 = gxh * xh;
#pragma unroll
      for (int m = 1; m <= 8; m <<= 1) { s1 = s1 + vshfl_xor(s1, m); s2 = s2 + vshfl_xor(s2, m); }
      if (l16 == 0) {
#pragma unroll
        for (int r = 0; r < 4; ++r) {
          red2[quad * 32 + r * 8 + wave]     = s1[r];
          red2[quad * 32 + r * 8 + 4 + wave] = s2[r];
        }
      }
    }
    __syncthreads();   // S3
    f32x4 grad;
#pragma unroll
    for (int r = 0; r < 4; ++r) {
      f32x4 a = *(const f32x4*)&red2[quad * 32 + r * 8];
      f32x4 c = *(const f32x4*)&red2[quad * 32 + r * 8 + 4];
      float S1v = a[0] + a[1] + a[2] + a[3];
      float S2v = c[0] + c[1] + c[2] + c[3];
      grad[r] = (64.0f * gxh[r] - S1v - xh[r] * S2v) * (rstd[r] * (1.0f / 64.0f));
    }
#pragma unroll
    for (int r = 0; r < 4; ++r) {
      float sk = sig_s[quad * 4 + r];
      gradT[dcol * 40 + quad * 4 + r] = f2bf(sk * grad[r]);
    }
    __syncthreads();   // S4

    // ---- correction MFMA + W1 update + b1 update ----
    bf16x8 fA = __builtin_bit_cast(bf16x8, *(const u16x8*)&coefA[l16 * 40 + quad * 8]);
    bf16x8 fG = __builtin_bit_cast(bf16x8, *(const u16x8*)&gradT[(wave * 16 + l16) * 40 + quad * 8]);
    f32x4 zb = __builtin_amdgcn_mfma_f32_16x16x32_bf16(fA, fG, zq, 0, 0, 0);
#pragma unroll
    for (int r = 0; r < 4; ++r) zb[r] += b1_reg;
    {
      bf16x8 fX = __builtin_bit_cast(bf16x8, *(const u16x8*)&xkT[(wave * 16 + l16) * 40 + quad * 8]);
#pragma unroll
      for (int m = 0; m < 4; ++m) {
        bf16x8 fGm = __builtin_bit_cast(bf16x8, *(const u16x8*)&gradT[(m * 16 + l16) * 40 + quad * 8]);
        master[m] = __builtin_amdgcn_mfma_f32_16x16x32_bf16(fGm, fX, master[m], 0, 0, 0);
      }
      float bs = 0.f;
#pragma unroll
      for (int j = 0; j < 8; ++j) bs += (float)fG[j];
      bs += __shfl_xor(bs, 16, 64);
      bs += __shfl_xor(bs, 32, 64);
      b1_reg -= tok15 * bs;
    }
    // ---- Zbar LN (round 3) ----
    {
      f32x4 s1 = zb, s2 = zb * zb;
#pragma unroll
      for (int m = 1; m <= 8; m <<= 1) { s1 = s1 + vshfl_xor(s1, m); s2 = s2 + vshfl_xor(s2, m); }
      if (l16 == 0) {
#pragma unroll
        for (int r = 0; r < 4; ++r) {
          red3[quad * 32 + r * 8 + wave]     = s1[r];
          red3[quad * 32 + r * 8 + 4 + wave] = s2[r];
        }
      }
    }
    __syncthreads();   // S5
#pragma unroll
    for (int r = 0; r < 4; ++r) {
      f32x4 a = *(const f32x4*)&red3[quad * 32 + r * 8];
      f32x4 c = *(const f32x4*)&red3[quad * 32 + r * 8 + 4];
      float S = a[0] + a[1] + a[2] + a[3];
      float SS = c[0] + c[1] + c[2] + c[3];
      float mu2 = S * (1.0f / 64.0f);
      float var2 = SS * (1.0f / 64.0f) - mu2 * mu2;
      float rstd2 = 1.0f / sqrtf(var2 + 1e-6f);
      float xq_pass = bf2f(xkq[(16 + quad * 4 + r) * 72 + dcol]);
      float yv = xq_pass + gamma_r * ((zb[r] - mu2) * rstd2) + beta_r;
      Y[((size_t)(b * L_ + n * KK_ + quad * 4 + r)) * HS_ + h * HD_ + dcol] = yv;
    }
#pragma unroll
    for (int m = 0; m < 4; ++m)
#pragma unroll
      for (int r = 0; r < 4; ++r)
        W1t[(m * 16 + quad * 4 + r) * 72 + dcol] = f2bf(master[m][r]);
    __syncthreads();   // S6
  }
}

// ---------------- post-norm (LN over HS=2048) -> bf16 ----------------
__global__ __launch_bounds__(256) void postnorm(const float* __restrict__ Yin,
                                                const float* __restrict__ w,
                                                const float* __restrict__ bb,
                                                u16* __restrict__ Yn) {
  __shared__ float red[8];
  int row = blockIdx.x, tid = threadIdx.x;
  const float* x = Yin + (size_t)row * HS_ + tid * 8;
  float4 v0 = *(const float4*)(x);
  float4 v1 = *(const float4*)(x + 4);
  float s  = v0.x + v0.y + v0.z + v0.w + v1.x + v1.y + v1.z + v1.w;
  float ss = v0.x*v0.x + v0.y*v0.y + v0.z*v0.z + v0.w*v0.w
           + v1.x*v1.x + v1.y*v1.y + v1.z*v1.z + v1.w*v1.w;
#pragma unroll
  for (int m = 32; m > 0; m >>= 1) { s += __shfl_xor(s, m, 64); ss += __shfl_xor(ss, m, 64); }
  int wave = tid >> 6, lane = tid & 63;
  if (lane == 0) { red[wave] = s; red[4 + wave] = ss; }
  __syncthreads();
  float S  = red[0] + red[1] + red[2] + red[3];
  float SS = red[4] + red[5] + red[6] + red[7];
  float mu = S * (1.f / 2048.f);
  float var = SS * (1.f / 2048.f) - mu * mu;
  float rstd = 1.f / sqrtf(var + 1e-6f);
  const float* wp = w + tid * 8;
  const float* bp = bb + tid * 8;
  float vals[8] = {v0.x, v0.y, v0.z, v0.w, v1.x, v1.y, v1.z, v1.w};
  u16x8 o;
#pragma unroll
  for (int t = 0; t < 8; ++t) o[t] = f2bf(wp[t] * ((vals[t] - mu) * rstd) + bp[t]);
  *(u16x8*)(Yn + (size_t)row * HS_ + tid * 8) = o;
}

extern "C" void kernel_launch(void* const* d_in, const int* in_sizes, int n_in,
                              void* d_out, int out_size, void* d_ws, size_t ws_size,
                              hipStream_t stream) {
  (void)in_sizes; (void)n_in; (void)out_size; (void)ws_size;
  const float* hidden = (const float*)d_in[0];
  const float* q_w = (const float*)d_in[2];
  const float* k_w = (const float*)d_in[3];
  const float* v_w = (const float*)d_in[4];
  const float* o_w = (const float*)d_in[5];
  const float* W1  = (const float*)d_in[6];
  const float* b1i = (const float*)d_in[7];
  const float* lnw = (const float*)d_in[8];
  const float* lnb = (const float*)d_in[9];
  const float* lrw = (const float*)d_in[10];
  const float* lrb = (const float*)d_in[11];
  const float* lti = (const float*)d_in[12];
  const float* pnw = (const float*)d_in[13];
  const float* pnb = (const float*)d_in[14];
  float* out = (float*)d_out;

  char* w = (char*)d_ws;
  u16* hsb  = (u16*)w;  w += (size_t)16777216 * 2;   // 32 MB; reused as Yn
  u16* wb   = (u16*)w;  w += (size_t)4194304 * 2;    // 8 MB (q/k/v/o reuse)
  u16* lrwb = (u16*)w;  w += (size_t)65536 * 2;
  u16* XQb  = (u16*)w;  w += (size_t)16777216 * 2;
  u16* XKb  = (u16*)w;  w += (size_t)16777216 * 2;
  u16* XVb  = (u16*)w;  w += (size_t)16777216 * 2;
  float* Sg = (float*)w; w += (size_t)M_ * NH_ * 4;
  u16* Yn = hsb;

  cast_f32_bf16<<<8192, 256, 0, stream>>>(hidden, hsb, 16777216);
  cast_f32_bf16<<<32, 256, 0, stream>>>(lrw, lrwb, 65536);

  sig_kernel<<<128, 256, 0, stream>>>(hsb, lrwb, lrb, Sg);

  dim3 gg(M_ / BM, HS_ / BN);
  cast_f32_bf16<<<2048, 256, 0, stream>>>(q_w, wb, 4194304);
  gemm_nt<true><<<gg, 256, 0, stream>>>(hsb, wb, XQb, M_, HS_, HS_);
  cast_f32_bf16<<<2048, 256, 0, stream>>>(k_w, wb, 4194304);
  gemm_nt<true><<<gg, 256, 0, stream>>>(hsb, wb, XKb, M_, HS_, HS_);
  cast_f32_bf16<<<2048, 256, 0, stream>>>(v_w, wb, 4194304);
  gemm_nt<true><<<gg, 256, 0, stream>>>(hsb, wb, XVb, M_, HS_, HS_);

  ttt_scan_mfma<<<128, 256, 0, stream>>>(XQb, XKb, XVb, Sg, W1, b1i, lnw, lnb, lti, out);

  postnorm<<<8192, 256, 0, stream>>>(out, pnw, pnb, Yn);

  cast_f32_bf16<<<2048, 256, 0, stream>>>(o_w, wb, 4194304);
  gemm_nt<false><<<gg, 256, 0, stream>>>(Yn, wb, out, M_, HS_, HS_);
}